// Round 1
// baseline (299.595 us; speedup 1.0000x reference)
//
#include <hip/hip_runtime.h>
#include <math.h>

#define NP 3136
#define NC 256
#define NB 16
#define HH 56
#define OW 224

// ---------------- Stage 1: Mahalanobis distance ----------------
// One block per p. 4 waves split 256 rows of M = inv_cov[p].
// Lane l of each wave holds delta[d][b] for d = 4l..4l+3, all 16 b, in regs.
// Per row c: wave loads M[c][:] as one coalesced float4/lane, computes
// s[b] = sum_j m_j * dreg[j][b], then z[b] += delta[c][b] * s[b].
// d2[b] = sum over lanes & waves of z[b].
__global__ __launch_bounds__(256) void k_dist(const float* __restrict__ emb,
                                              const float* __restrict__ means,
                                              const float* __restrict__ icov,
                                              float* __restrict__ dist) {
  __shared__ float dlds[NC][20];  // [c][b], padded to 20 (16B-aligned float4 rows)
  __shared__ float zbuf[4][16];

  const int bid = blockIdx.x;
  const int p = (bid & 7) * (NP >> 3) + (bid >> 3);  // XCD swizzle (3136 % 8 == 0)
  const int t = threadIdx.x;
  const int lane = t & 63;
  const int wv = t >> 6;

  // stage delta[c][b] = emb[b][c][p] - means[p][c]; thread t owns c = t
  {
    const int c = t;
    const float mn = means[(size_t)p * NC + c];
    const float* ep = emb + (size_t)c * NP + p;
    #pragma unroll
    for (int q = 0; q < 4; ++q) {
      float4 v;
      v.x = ep[(size_t)(4 * q + 0) * NC * NP] - mn;
      v.y = ep[(size_t)(4 * q + 1) * NC * NP] - mn;
      v.z = ep[(size_t)(4 * q + 2) * NC * NP] - mn;
      v.w = ep[(size_t)(4 * q + 3) * NC * NP] - mn;
      *reinterpret_cast<float4*>(&dlds[c][4 * q]) = v;
    }
  }
  __syncthreads();

  // per-lane delta registers: d = 4*lane + j
  float dreg[4][16];
  #pragma unroll
  for (int j = 0; j < 4; ++j) {
    #pragma unroll
    for (int q = 0; q < 4; ++q) {
      const float4 v = *reinterpret_cast<const float4*>(&dlds[4 * lane + j][4 * q]);
      dreg[j][4 * q + 0] = v.x;
      dreg[j][4 * q + 1] = v.y;
      dreg[j][4 * q + 2] = v.z;
      dreg[j][4 * q + 3] = v.w;
    }
  }

  float z[16];
  #pragma unroll
  for (int b = 0; b < 16; ++b) z[b] = 0.f;

  const float* mrow = icov + (size_t)p * NC * NC + (size_t)(wv * 64) * NC + 4 * lane;
  float4 mcur = *reinterpret_cast<const float4*>(mrow);
  for (int r = 0; r < 64; ++r) {
    // prefetch next row (guarded, uniform)
    const float4 mnext =
        *reinterpret_cast<const float4*>(mrow + (size_t)(r < 63 ? (r + 1) : r) * NC);
    const int c = wv * 64 + r;
    float s[16];
    #pragma unroll
    for (int b = 0; b < 16; ++b) s[b] = mcur.x * dreg[0][b];
    #pragma unroll
    for (int b = 0; b < 16; ++b) s[b] = fmaf(mcur.y, dreg[1][b], s[b]);
    #pragma unroll
    for (int b = 0; b < 16; ++b) s[b] = fmaf(mcur.z, dreg[2][b], s[b]);
    #pragma unroll
    for (int b = 0; b < 16; ++b) s[b] = fmaf(mcur.w, dreg[3][b], s[b]);
    #pragma unroll
    for (int q = 0; q < 4; ++q) {
      const float4 dc = *reinterpret_cast<const float4*>(&dlds[c][4 * q]);
      z[4 * q + 0] = fmaf(dc.x, s[4 * q + 0], z[4 * q + 0]);
      z[4 * q + 1] = fmaf(dc.y, s[4 * q + 1], z[4 * q + 1]);
      z[4 * q + 2] = fmaf(dc.z, s[4 * q + 2], z[4 * q + 2]);
      z[4 * q + 3] = fmaf(dc.w, s[4 * q + 3], z[4 * q + 3]);
    }
    mcur = mnext;
  }

  // reduce z across 64 lanes (butterfly), then across waves via LDS
  #pragma unroll
  for (int b = 0; b < 16; ++b) {
    float v = z[b];
    #pragma unroll
    for (int off = 32; off > 0; off >>= 1) v += __shfl_xor(v, off, 64);
    z[b] = v;
  }
  if (lane == 0) {
    #pragma unroll
    for (int b = 0; b < 16; ++b) zbuf[wv][b] = z[b];
  }
  __syncthreads();
  if (t < 16) {
    const float d2 = zbuf[0][t] + zbuf[1][t] + zbuf[2][t] + zbuf[3][t];
    dist[(size_t)t * NP + p] = sqrtf(d2);
  }
}

// ---------------- Stage 2a: bilinear resize 56 -> 224 (align_corners=False) ----
__global__ __launch_bounds__(256) void k_resize(const float* __restrict__ dist,
                                                float* __restrict__ out,
                                                unsigned int* __restrict__ mm) {
  const int idx = blockIdx.x * 256 + threadIdx.x;
  if (idx == 0) { mm[0] = 0x7f800000u; mm[1] = 0u; }  // +inf, 0 (scores >= 0)
  if (idx >= NB * OW * OW) return;
  const int x = idx % OW;
  const int y = (idx / OW) % OW;
  const int b = idx / (OW * OW);
  const float sy = y * 0.25f - 0.375f;
  const float sx = x * 0.25f - 0.375f;
  const int y0 = (int)floorf(sy);
  const int x0 = (int)floorf(sx);
  const float fy = sy - (float)y0;
  const float fx = sx - (float)x0;
  const int y0c = min(max(y0, 0), HH - 1), y1c = min(max(y0 + 1, 0), HH - 1);
  const int x0c = min(max(x0, 0), HH - 1), x1c = min(max(x0 + 1, 0), HH - 1);
  const float* db = dist + (size_t)b * NP;
  const float v00 = db[y0c * HH + x0c], v01 = db[y0c * HH + x1c];
  const float v10 = db[y1c * HH + x0c], v11 = db[y1c * HH + x1c];
  const float v0 = v00 + fx * (v01 - v00);
  const float v1 = v10 + fx * (v11 - v10);
  out[idx] = v0 + fy * (v1 - v0);
}

// ---------------- Stage 2b: separable 33-tap gaussian, unnormalized weights ----
// (normalization constant cancels in the final min-max normalization)
__global__ __launch_bounds__(256) void k_rowblur(const float* __restrict__ in,
                                                 float* __restrict__ out) {
  __shared__ float w[33];
  __shared__ float row[256];
  const int t = threadIdx.x;
  const int by = blockIdx.x;  // b*224 + y
  const float* rp = in + (size_t)by * OW;
  if (t < 33) {
    const float d = (float)(t - 16);
    w[t] = expf(-d * d * (1.f / 32.f));
  }
  int xi = t - 16;  // [-16, 239]
  xi = (xi < 0) ? (-xi - 1) : xi;
  xi = (xi >= OW) ? (2 * OW - 1 - xi) : xi;
  row[t] = rp[xi];
  __syncthreads();
  if (t < OW) {
    float a = 0.f;
    #pragma unroll
    for (int k = 0; k < 33; ++k) a = fmaf(w[k], row[t + k], a);
    out[(size_t)by * OW + t] = a;
  }
}

__global__ __launch_bounds__(256) void k_colblur(const float* __restrict__ in,
                                                 float* __restrict__ out,
                                                 unsigned int* __restrict__ mm) {
  __shared__ float w[33];
  __shared__ float red[4][2];
  const int t = threadIdx.x;
  const int by = blockIdx.x;  // b*224 + y
  const int b = by / OW, y = by % OW;
  if (t < 33) {
    const float d = (float)(t - 16);
    w[t] = expf(-d * d * (1.f / 32.f));
  }
  __syncthreads();
  float a = 0.f;
  const float* bp = in + (size_t)b * OW * OW;
  if (t < OW) {
    #pragma unroll
    for (int k = 0; k < 33; ++k) {
      int yi = y + k - 16;
      yi = (yi < 0) ? (-yi - 1) : yi;
      yi = (yi >= OW) ? (2 * OW - 1 - yi) : yi;
      a = fmaf(w[k], bp[(size_t)yi * OW + t], a);
    }
    out[(size_t)by * OW + t] = a;
  }
  // block min/max -> global atomics (positive floats monotone as uints)
  float mnv = (t < OW) ? a : 3.0e38f;
  float mxv = (t < OW) ? a : 0.f;
  #pragma unroll
  for (int off = 32; off > 0; off >>= 1) {
    mnv = fminf(mnv, __shfl_xor(mnv, off, 64));
    mxv = fmaxf(mxv, __shfl_xor(mxv, off, 64));
  }
  const int lane = t & 63, wv = t >> 6;
  if (lane == 0) { red[wv][0] = mnv; red[wv][1] = mxv; }
  __syncthreads();
  if (t == 0) {
    const float m0 = fminf(fminf(red[0][0], red[1][0]), fminf(red[2][0], red[3][0]));
    const float m1 = fmaxf(fmaxf(red[0][1], red[1][1]), fmaxf(red[2][1], red[3][1]));
    atomicMin(&mm[0], __float_as_uint(m0));
    atomicMax(&mm[1], __float_as_uint(m1));
  }
}

// ---------------- Stage 2c: normalize ----------------
__global__ __launch_bounds__(256) void k_norm(const float* __restrict__ in,
                                              const unsigned int* __restrict__ mm,
                                              float* __restrict__ out, int n) {
  const float mn = __uint_as_float(mm[0]);
  const float mx = __uint_as_float(mm[1]);
  const float inv = 1.f / (mx - mn);
  for (int i = blockIdx.x * 256 + threadIdx.x; i < n; i += gridDim.x * 256)
    out[i] = (in[i] - mn) * inv;
}

extern "C" void kernel_launch(void* const* d_in, const int* in_sizes, int n_in,
                              void* d_out, int out_size, void* d_ws, size_t ws_size,
                              hipStream_t stream) {
  const float* emb = (const float*)d_in[0];    // [16,256,3136]
  const float* means = (const float*)d_in[1];  // [3136,256]
  const float* icov = (const float*)d_in[2];   // [3136,256,256]
  float* out = (float*)d_out;                  // [16,224,224]

  char* ws = (char*)d_ws;
  float* dist = (float*)ws;                               // 16*3136 floats
  float* tmp1 = (float*)(ws + 204800);                    // 16*224*224 floats
  unsigned int* mm = (unsigned int*)(ws + 204800 + 3211264);

  k_dist<<<NP, 256, 0, stream>>>(emb, means, icov, dist);
  k_resize<<<(NB * OW * OW + 255) / 256, 256, 0, stream>>>(dist, tmp1, mm);
  k_rowblur<<<NB * OW, 256, 0, stream>>>(tmp1, out);     // out used as scratch
  k_colblur<<<NB * OW, 256, 0, stream>>>(out, tmp1, mm);
  k_norm<<<2048, 256, 0, stream>>>(tmp1, mm, out, NB * OW * OW);
}

// Round 2
// 269.990 us; speedup vs baseline: 1.1097x; 1.1097x over previous
//
#include <hip/hip_runtime.h>
#include <math.h>

#define NP 3136
#define NC 256
#define NB 16
#define HH 56
#define OW 224

// ---------------- Stage 1: Mahalanobis distance ----------------
// One block per p. 4 waves split 256 rows of M = inv_cov[p].
// Lane l holds delta[4l..4l+3][b] in regs (dreg). Per row c the wave loads
// M[c][:] as one coalesced float4/lane (4-deep prefetched), computes
// s[b] = sum_j m_j * dreg[j][b], then z[b] += delta[c][b] * s[b] via a
// conflict-free c-major LDS broadcast. Butterfly + LDS reduce at the end.
__device__ __forceinline__ void rowstep(const float4 mv, const int c,
                                        const float (&dreg)[4][16], float (&z)[16],
                                        const float (*dc_lds)[20]) {
  float s[16];
#pragma unroll
  for (int b = 0; b < 16; ++b) s[b] = mv.x * dreg[0][b];
#pragma unroll
  for (int b = 0; b < 16; ++b) s[b] = fmaf(mv.y, dreg[1][b], s[b]);
#pragma unroll
  for (int b = 0; b < 16; ++b) s[b] = fmaf(mv.z, dreg[2][b], s[b]);
#pragma unroll
  for (int b = 0; b < 16; ++b) s[b] = fmaf(mv.w, dreg[3][b], s[b]);
#pragma unroll
  for (int q = 0; q < 4; ++q) {
    const float4 dc = *reinterpret_cast<const float4*>(&dc_lds[c][4 * q]);
    z[4 * q + 0] = fmaf(dc.x, s[4 * q + 0], z[4 * q + 0]);
    z[4 * q + 1] = fmaf(dc.y, s[4 * q + 1], z[4 * q + 1]);
    z[4 * q + 2] = fmaf(dc.z, s[4 * q + 2], z[4 * q + 2]);
    z[4 * q + 3] = fmaf(dc.w, s[4 * q + 3], z[4 * q + 3]);
  }
}

__global__ __launch_bounds__(256) void k_dist(const float* __restrict__ emb,
                                              const float* __restrict__ means,
                                              const float* __restrict__ icov,
                                              float* __restrict__ dist) {
  __shared__ float dc_lds[NC][20];      // [c][b]+pad: broadcast reads (hot loop)
  __shared__ float db_lds[NB][NC + 8];  // [b][c]+pad: conflict-free dreg load
  __shared__ float zbuf[4][16];

  const int bid = blockIdx.x;
  const int p = (bid & 7) * (NP >> 3) + (bid >> 3);  // XCD swizzle (3136 % 8 == 0)
  const int t = threadIdx.x;
  const int lane = t & 63;
  const int wv = t >> 6;

  // stage delta[c][b] = emb[b][c][p] - means[p][c]; thread t owns c = t
  {
    const int c = t;
    const float mn = means[(size_t)p * NC + c];
    const float* ep = emb + (size_t)c * NP + p;
    float d[16];
#pragma unroll
    for (int b = 0; b < 16; ++b) d[b] = ep[(size_t)b * (NC * NP)] - mn;
#pragma unroll
    for (int q = 0; q < 4; ++q) {
      const float4 v = make_float4(d[4 * q], d[4 * q + 1], d[4 * q + 2], d[4 * q + 3]);
      *reinterpret_cast<float4*>(&dc_lds[c][4 * q]) = v;
    }
#pragma unroll
    for (int b = 0; b < 16; ++b) db_lds[b][c] = d[b];
  }
  __syncthreads();

  // per-lane delta registers from b-major copy (contiguous -> no conflicts)
  float dreg[4][16];
#pragma unroll
  for (int b = 0; b < 16; ++b) {
    const float4 v = *reinterpret_cast<const float4*>(&db_lds[b][4 * lane]);
    dreg[0][b] = v.x; dreg[1][b] = v.y; dreg[2][b] = v.z; dreg[3][b] = v.w;
  }

  float z[16];
#pragma unroll
  for (int b = 0; b < 16; ++b) z[b] = 0.f;

  const float* mbase = icov + (size_t)p * (NC * NC) + (size_t)(wv * 64) * NC + 4 * lane;
#define LOADM(r) (*reinterpret_cast<const float4*>(mbase + (size_t)(r) * NC))

  float4 m0 = LOADM(0), m1 = LOADM(1), m2 = LOADM(2), m3 = LOADM(3);
  for (int rb = 0; rb < 64; rb += 4) {
    const int r4 = (rb + 4 < 64) ? rb + 4 : 63;
    const int r5 = (rb + 5 < 64) ? rb + 5 : 63;
    const int r6 = (rb + 6 < 64) ? rb + 6 : 63;
    const int r7 = (rb + 7 < 64) ? rb + 7 : 63;
    const float4 n0 = LOADM(r4);
    const float4 n1 = LOADM(r5);
    const float4 n2 = LOADM(r6);
    const float4 n3 = LOADM(r7);
    rowstep(m0, wv * 64 + rb + 0, dreg, z, dc_lds);
    rowstep(m1, wv * 64 + rb + 1, dreg, z, dc_lds);
    rowstep(m2, wv * 64 + rb + 2, dreg, z, dc_lds);
    rowstep(m3, wv * 64 + rb + 3, dreg, z, dc_lds);
    m0 = n0; m1 = n1; m2 = n2; m3 = n3;
  }
#undef LOADM

  // reduce z across 64 lanes (butterfly), then across waves via LDS
#pragma unroll
  for (int b = 0; b < 16; ++b) {
    float v = z[b];
#pragma unroll
    for (int off = 32; off > 0; off >>= 1) v += __shfl_xor(v, off, 64);
    z[b] = v;
  }
  if (lane == 0) {
#pragma unroll
    for (int b = 0; b < 16; ++b) zbuf[wv][b] = z[b];
  }
  __syncthreads();
  if (t < 16) {
    const float d2 = zbuf[0][t] + zbuf[1][t] + zbuf[2][t] + zbuf[3][t];
    dist[(size_t)t * NP + p] = sqrtf(d2);
  }
}

// ---------------- Stage 2a: fused bilinear-resize + row gaussian blur --------
// Block = one output row (b, y) of the 224x224 image. Each thread computes one
// resized sample (with x-reflection for the blur halo) directly from dist,
// then threads t<224 convolve. Unnormalized weights (constant cancels in the
// final min-max normalization).
__global__ __launch_bounds__(256) void k_rowblur(const float* __restrict__ dist,
                                                 float* __restrict__ out,
                                                 unsigned int* __restrict__ mm) {
  __shared__ float w[33];
  __shared__ float row[256];
  const int t = threadIdx.x;
  const int by = blockIdx.x;  // b*224 + y
  const int b = by / OW, y = by - b * OW;
  if (by == 0 && t == 0) { mm[0] = 0x7f800000u; mm[1] = 0u; }  // init for colblur
  if (t < 33) {
    const float d = (float)(t - 16);
    w[t] = expf(-d * d * (1.f / 32.f));
  }
  int xi = t - 16;  // [-16, 239] -> reflect into [0, 224)
  xi = (xi < 0) ? (-xi - 1) : xi;
  xi = (xi >= OW) ? (2 * OW - 1 - xi) : xi;
  const float sy = y * 0.25f - 0.375f;
  const float sx = xi * 0.25f - 0.375f;
  const int y0 = (int)floorf(sy), x0 = (int)floorf(sx);
  const float fy = sy - (float)y0, fx = sx - (float)x0;
  const int y0c = y0 < 0 ? 0 : (y0 > HH - 1 ? HH - 1 : y0);
  const int y1c = (y0 + 1) > HH - 1 ? HH - 1 : (y0 + 1 < 0 ? 0 : y0 + 1);
  const int x0c = x0 < 0 ? 0 : (x0 > HH - 1 ? HH - 1 : x0);
  const int x1c = (x0 + 1) > HH - 1 ? HH - 1 : (x0 + 1 < 0 ? 0 : x0 + 1);
  const float* db = dist + (size_t)b * NP;
  const float v00 = db[y0c * HH + x0c], v01 = db[y0c * HH + x1c];
  const float v10 = db[y1c * HH + x0c], v11 = db[y1c * HH + x1c];
  const float v0 = v00 + fx * (v01 - v00);
  const float v1 = v10 + fx * (v11 - v10);
  row[t] = v0 + fy * (v1 - v0);
  __syncthreads();
  if (t < OW) {
    float a = 0.f;
#pragma unroll
    for (int k = 0; k < 33; ++k) a = fmaf(w[k], row[t + k], a);
    out[(size_t)by * OW + t] = a;
  }
}

// ---------------- Stage 2b: column gaussian blur + global min/max ------------
__global__ __launch_bounds__(256) void k_colblur(const float* __restrict__ in,
                                                 float* __restrict__ out,
                                                 unsigned int* __restrict__ mm) {
  __shared__ float w[33];
  __shared__ float red[4][2];
  const int t = threadIdx.x;
  const int by = blockIdx.x;  // b*224 + y
  const int b = by / OW, y = by - b * OW;
  if (t < 33) {
    const float d = (float)(t - 16);
    w[t] = expf(-d * d * (1.f / 32.f));
  }
  __syncthreads();
  float a = 0.f;
  const float* bp = in + (size_t)b * OW * OW;
  if (t < OW) {
#pragma unroll
    for (int k = 0; k < 33; ++k) {
      int yi = y + k - 16;
      yi = (yi < 0) ? (-yi - 1) : yi;
      yi = (yi >= OW) ? (2 * OW - 1 - yi) : yi;
      a = fmaf(w[k], bp[(size_t)yi * OW + t], a);
    }
    out[(size_t)by * OW + t] = a;
  }
  // block min/max -> global atomics (non-negative floats monotone as uints)
  float mnv = (t < OW) ? a : 3.0e38f;
  float mxv = (t < OW) ? a : 0.f;
#pragma unroll
  for (int off = 32; off > 0; off >>= 1) {
    mnv = fminf(mnv, __shfl_xor(mnv, off, 64));
    mxv = fmaxf(mxv, __shfl_xor(mxv, off, 64));
  }
  const int lane = t & 63, wv = t >> 6;
  if (lane == 0) { red[wv][0] = mnv; red[wv][1] = mxv; }
  __syncthreads();
  if (t == 0) {
    const float m0 = fminf(fminf(red[0][0], red[1][0]), fminf(red[2][0], red[3][0]));
    const float m1 = fmaxf(fmaxf(red[0][1], red[1][1]), fmaxf(red[2][1], red[3][1]));
    atomicMin(&mm[0], __float_as_uint(m0));
    atomicMax(&mm[1], __float_as_uint(m1));
  }
}

// ---------------- Stage 2c: normalize (float4) ----------------
__global__ __launch_bounds__(256) void k_norm(const float4* __restrict__ in,
                                              const unsigned int* __restrict__ mm,
                                              float4* __restrict__ out) {
  const int i = blockIdx.x * 256 + threadIdx.x;  // 200704 float4s exactly
  const float mn = __uint_as_float(mm[0]);
  const float mx = __uint_as_float(mm[1]);
  const float inv = 1.f / (mx - mn);
  const float4 v = in[i];
  out[i] = make_float4((v.x - mn) * inv, (v.y - mn) * inv,
                       (v.z - mn) * inv, (v.w - mn) * inv);
}

extern "C" void kernel_launch(void* const* d_in, const int* in_sizes, int n_in,
                              void* d_out, int out_size, void* d_ws, size_t ws_size,
                              hipStream_t stream) {
  const float* emb = (const float*)d_in[0];    // [16,256,3136]
  const float* means = (const float*)d_in[1];  // [3136,256]
  const float* icov = (const float*)d_in[2];   // [3136,256,256]
  float* out = (float*)d_out;                  // [16,224,224]

  char* ws = (char*)d_ws;
  float* dist = (float*)ws;                               // 16*3136 floats
  float* tmp1 = (float*)(ws + 204800);                    // 16*224*224 floats
  unsigned int* mm = (unsigned int*)(ws + 204800 + 3211264);

  k_dist<<<NP, 256, 0, stream>>>(emb, means, icov, dist);
  k_rowblur<<<NB * OW, 256, 0, stream>>>(dist, out, mm);   // out as scratch
  k_colblur<<<NB * OW, 256, 0, stream>>>(out, tmp1, mm);
  k_norm<<<NB * OW * OW / 1024, 256, 0, stream>>>((const float4*)tmp1, mm,
                                                  (float4*)out);
}